// Round 2
// baseline (122.907 us; speedup 1.0000x reference)
//
#include <hip/hip_runtime.h>
#include <hip/hip_bf16.h>
#include <stdint.h>

#define NIMG 8
#define CIN  64
#define HWI  12544      // 112*112
#define COUT 128

typedef int v4i __attribute__((ext_vector_type(4)));

// fake-quant to int grid: round(x*inv) clamped to [lo,hi]
static __device__ __forceinline__ int q8(float x, float inv, float lo, float hi) {
    float t = rintf(x * inv);
    t = fminf(fmaxf(t, lo), hi);
    return (int)t;
}

// funnel shift: bytes of ({hi,lo} >> sh) — compiler emits v_alignbit_b32
static __device__ __forceinline__ uint32_t funnel(uint32_t hi, uint32_t lo, int sh) {
    return (uint32_t)(((((uint64_t)hi) << 32) | (uint64_t)lo) >> sh);
}

// signed-byte dot4: HW v_dot4_i32_i8 when available (1 inst vs ~16)
static __device__ __forceinline__ int dot4(uint32_t a, uint32_t b, int c) {
#if __has_builtin(__builtin_amdgcn_sdot4)
    return __builtin_amdgcn_sdot4((int)a, (int)b, c, false);
#else
    int acc = c;
    #pragma unroll
    for (int i = 0; i < 4; ++i)
        acc += (int)(int8_t)(a >> (8*i)) * (int)(int8_t)(b >> (8*i));
    return acc;
#endif
}

// ---------------------------------------------------------------------------
// Single fused kernel (1 row/block, 896 blocks). No workspace, no wprep:
// each thread quantizes exactly the 64 weights forming its own MFMA
// fragments (2 co x 16 k of w2 + same of wsc) — 8 float4 L2 loads + ~400
// VALU ops, overlapped with phase-1 x loads. offs[co] compensation
// (128 * sum_k w2q[co][k], for the biased yq-128 B operand) is rebuilt via
// __shfl_xor over lanes {ln, ln+16, ln+32, ln+48}, which share co and
// jointly cover k=0..63; it is then folded into the MFMA C operand
// (integer accumulate is exact).
//
//   XCD swizzle: n = bid&7, h = bid>>3 — each image (x slice 3.2MB < 4MB L2)
//   stays on one XCD with all 112 row-blocks co-resident.
//   ph0a: depthwise taps; ph0b: per-thread weight-fragment quant + offs
//   ph1: x loads in 3 batches of 7 float4 -> quant -> tile
//   ph2: depthwise 3x3 (sdot4) + relu-quant -> Bl int8 [112 px][144]
//        (k 0..63 = yq-128 biased, 64..127 = xq)
//   ph3: mfma_i32_16x16x64_i8, A=activations, B=weights; D regs/lane = 4
//        consecutive px of one co row -> float4 stores. inv_sadd folded
//        into the two scale factors (epilogue 8 VALU ops/элem).
// LDS = 22272 + 16128 = 38400 B -> 4 blocks/CU; launch_bounds(256,4).
// ---------------------------------------------------------------------------
__global__ void __launch_bounds__(256, 4) fused_kernel(
    const float* __restrict__ x, const float* __restrict__ w1,
    const float* __restrict__ w2, const float* __restrict__ wsc,
    const float* __restrict__ sinp, const float* __restrict__ srelup,
    const float* __restrict__ saddp, const float* __restrict__ sw1p,
    const float* __restrict__ sw2p, const float* __restrict__ swscp,
    float* __restrict__ out)
{
    __shared__ int8_t tile[64 * 348];   // c-stride 348 B (87 dwords, odd)
    __shared__ int8_t Bl[112 * 144];    // px-stride 144 B (16B-aligned for b128)

    int bid = blockIdx.x;
    int n = bid & 7, h = bid >> 3;      // XCD-pinned image, sequential rows
    int tid = threadIdx.x;
    int wave = tid >> 6, lane = tid & 63;
    int lr = lane >> 4, ln = lane & 15;
    float sin_f = sinp[0];
    float inv_sin = 1.0f / sin_f;

    // ---- phase 0a: depthwise taps for this thread's channel ----
    int c = lane;
    float isw1 = 1.0f / sw1p[0];
    uint32_t wp[3];
    #pragma unroll
    for (int ky = 0; ky < 3; ++ky) {
        uint32_t pk = 0;
        #pragma unroll
        for (int kx = 0; kx < 3; ++kx) {
            int q = q8(w1[c*9 + ky*3 + kx], isw1, -128.0f, 127.0f);
            pk |= (uint32_t)(q & 255) << (8*kx);
        }
        wp[ky] = pk;
    }

    // ---- phase 0b: quantize this thread's own 1x1-weight fragments ----
    // a[mi][half]: co = (wave*2+mi)*16 + ln, k-bytes = half*64 + lr*16 .. +15
    v4i a[2][2];
    int ofsv[2];
    {
        float inv2 = 1.0f / sw2p[0];
        float invs = 1.0f / swscp[0];
        #pragma unroll
        for (int mi = 0; mi < 2; ++mi) {
            int co = (wave*2 + mi)*16 + ln;
            const float* w2p = w2 + co*64 + lr*16;
            const float* wsp = wsc + co*64 + lr*16;
            int pk2[4], pks[4];
            int partial = 0;
            #pragma unroll
            for (int d = 0; d < 4; ++d) {
                float4 f2 = *(const float4*)(w2p + d*4);
                float4 fs = *(const float4*)(wsp + d*4);
                float a2[4] = {f2.x, f2.y, f2.z, f2.w};
                float as[4] = {fs.x, fs.y, fs.z, fs.w};
                uint32_t p2 = 0, ps = 0;
                #pragma unroll
                for (int j = 0; j < 4; ++j) {
                    int q2 = q8(a2[j], inv2, -128.f, 127.f);
                    int qs = q8(as[j], invs, -128.f, 127.f);
                    partial += q2;
                    p2 |= (uint32_t)(q2 & 255) << (8*j);
                    ps |= (uint32_t)(qs & 255) << (8*j);
                }
                pk2[d] = (int)p2; pks[d] = (int)ps;
            }
            a[mi][0] = (v4i){pk2[0], pk2[1], pk2[2], pk2[3]};
            a[mi][1] = (v4i){pks[0], pks[1], pks[2], pks[3]};
            // sum over k=0..63: lanes {ln, ln+16, ln+32, ln+48} share co
            partial += __shfl_xor(partial, 16);
            partial += __shfl_xor(partial, 32);
            ofsv[mi] = partial << 7;
        }
    }

    // ---- phase 1: 3 batches of 7 float4 (28 VGPRs in flight) ----
    #pragma unroll
    for (int b = 0; b < 3; ++b) {
        float4 vals[7];
        #pragma unroll
        for (int i = 0; i < 7; ++i) {
            int id = tid + (b*7 + i)*256;
            int cc = id / 84; int rem = id - cc*84;
            int r = rem / 28; int seg = rem - r*28;
            int grow = h + r - 1;
            vals[i] = make_float4(0.f, 0.f, 0.f, 0.f);
            if ((unsigned)grow < 112u)
                vals[i] = *(const float4*)(x + ((size_t)(n*64 + cc) * HWI + grow*112 + seg*4));
        }
        #pragma unroll
        for (int i = 0; i < 7; ++i) {
            int id = tid + (b*7 + i)*256;
            int cc = id / 84; int rem = id - cc*84;
            int r = rem / 28; int seg = rem - r*28;
            float vv[4] = {vals[i].x, vals[i].y, vals[i].z, vals[i].w};
            uint32_t pk = 0;
            #pragma unroll
            for (int e = 0; e < 4; ++e) {
                int q = q8(vv[e], inv_sin, -128.0f, 127.0f);
                pk |= (uint32_t)(q & 255) << (8*e);
            }
            *(uint32_t*)&tile[cc*348 + r*116 + seg*4] = pk;
        }
    }
    if (tid < 192) {  // zero pad cols 112..115 of each (c, r)
        int cc = tid / 3, r = tid - cc*3;
        *(uint32_t*)&tile[cc*348 + r*116 + 112] = 0;
    }
    __syncthreads();

    // ---- phase 2: depthwise 3x3 + relu-quant; int8 yq-128 / xq into Bl ----
    {
        int w0b = wave * 28;              // 28-px quarter of the row
        float r1 = (sin_f * sw1p[0]) / srelup[0];

        int base[3];
        #pragma unroll
        for (int r2 = 0; r2 < 3; ++r2) base[r2] = c*348 + r2*116;

        uint32_t Ar[3], Br[3], Cr[3];
        #pragma unroll
        for (int r2 = 0; r2 < 3; ++r2) {
            Ar[r2] = wave ? *(uint32_t*)&tile[base[r2] + w0b - 4] : 0u;
            Br[r2] = *(uint32_t*)&tile[base[r2] + w0b];
            Cr[r2] = *(uint32_t*)&tile[base[r2] + w0b + 4];
        }

        #pragma unroll
        for (int q = 0; q < 7; ++q) {
            int acc0 = 0, acc1 = 0, acc2 = 0, acc3 = 0;
            #pragma unroll
            for (int r2 = 0; r2 < 3; ++r2) {
                uint32_t d0 = funnel(Br[r2], Ar[r2], 24);
                uint32_t d1 = Br[r2];
                uint32_t d2 = funnel(Cr[r2], Br[r2], 8);
                uint32_t d3 = funnel(Cr[r2], Br[r2], 16);
                acc0 = dot4(d0, wp[r2], acc0);
                acc1 = dot4(d1, wp[r2], acc1);
                acc2 = dot4(d2, wp[r2], acc2);
                acc3 = dot4(d3, wp[r2], acc3);
            }
            int accs[4] = {acc0, acc1, acc2, acc3};
            uint32_t xdw = Br[1];
            int pxb = w0b + q*4;
            #pragma unroll
            for (int j = 0; j < 4; ++j) {
                float t = rintf((float)accs[j] * r1);
                t = fminf(fmaxf(t, 0.0f), 255.0f);
                Bl[(pxb + j)*144 + c]      = (int8_t)((int)t - 128);         // yq-128
                Bl[(pxb + j)*144 + 64 + c] = (int8_t)((xdw >> (8*j)) & 255); // xq
            }
            #pragma unroll
            for (int r2 = 0; r2 < 3; ++r2) { Ar[r2] = Br[r2]; Br[r2] = Cr[r2]; }
            if (q < 6) {
                #pragma unroll
                for (int r2 = 0; r2 < 3; ++r2)
                    Cr[r2] = *(uint32_t*)&tile[base[r2] + w0b + q*4 + 8];
            }
        }
    }
    __syncthreads();

    // ---- phase 3: GEMM (mfma, A=act B=weight) + requant, float4 stores ----
    {
        float sadd = saddp[0];
        float inv_sadd = 1.0f / sadd;
        float S2i  = (sw2p[0] * srelup[0]) * inv_sadd;
        float Ssci = (swscp[0] * sin_f)    * inv_sadd;

        size_t orow = (size_t)n*COUT*HWI + (size_t)h*112;

        for (int nt = 0; nt < 7; ++nt) {
            int px = nt*16 + ln;                     // A-fragment row index
            const int8_t* bp = &Bl[px*144 + lr*16];
            v4i b0 = *(const v4i*)bp;          // yq-128 bytes (k<64)
            v4i b1 = *(const v4i*)(bp + 64);   // xq bytes   (k>=64)
            int pxb = nt*16 + lr*4;                  // D rows: 4 consecutive px
            #pragma unroll
            for (int mi = 0; mi < 2; ++mi) {
                v4i z = {0, 0, 0, 0};
                v4i cini = {ofsv[mi], ofsv[mi], ofsv[mi], ofsv[mi]};
                // operand swap: A = activations, B = weights; offs in C operand
                v4i c2 = __builtin_amdgcn_mfma_i32_16x16x64_i8(b0, a[mi][0], cini, 0, 0, 0);
                v4i cs = __builtin_amdgcn_mfma_i32_16x16x64_i8(b1, a[mi][1], z, 0, 0, 0);
                int co = (wave*2 + mi)*16 + ln;
                float vr[4];
                #pragma unroll
                for (int r = 0; r < 4; ++r) {
                    float t = rintf(S2i * (float)c2[r] + Ssci * (float)cs[r]);
                    t = fminf(fmaxf(t, -128.0f), 127.0f);
                    vr[r] = t * sadd;
                }
                *(float4*)(out + orow + (size_t)co*HWI + pxb) =
                    make_float4(vr[0], vr[1], vr[2], vr[3]);
            }
        }
    }
}

// ---------------------------------------------------------------------------
extern "C" void kernel_launch(void* const* d_in, const int* in_sizes, int n_in,
                              void* d_out, int out_size, void* d_ws, size_t ws_size,
                              hipStream_t stream) {
    const float* x     = (const float*)d_in[0];
    const float* w1    = (const float*)d_in[1];
    const float* w2    = (const float*)d_in[2];
    const float* wsc   = (const float*)d_in[3];
    const float* sin   = (const float*)d_in[4];
    const float* srelu = (const float*)d_in[5];
    const float* sadd  = (const float*)d_in[6];
    const float* sw1   = (const float*)d_in[7];
    const float* sw2   = (const float*)d_in[8];
    const float* swsc  = (const float*)d_in[9];

    (void)d_ws; (void)ws_size;  // no workspace: weight quant fused per-block

    fused_kernel<<<NIMG * 112, 256, 0, stream>>>(x, w1, w2, wsc,
                                                 sin, srelu, sadd, sw1, sw2, swsc,
                                                 (float*)d_out);
}

// Round 4
// 117.100 us; speedup vs baseline: 1.0496x; 1.0496x over previous
//
#include <hip/hip_runtime.h>
#include <hip/hip_bf16.h>
#include <stdint.h>

#define NIMG 8
#define CIN  64
#define HWI  12544      // 112*112
#define COUT 128

typedef int   v4i __attribute__((ext_vector_type(4)));
typedef float v4f __attribute__((ext_vector_type(4)));   // native vec: ok for nontemporal builtins

// fake-quant to int grid: round(x*inv) clamped to [lo,hi]
static __device__ __forceinline__ int q8(float x, float inv, float lo, float hi) {
    float t = rintf(x * inv);
    t = fminf(fmaxf(t, lo), hi);
    return (int)t;
}

// funnel shift: bytes of ({hi,lo} >> sh) — compiler emits v_alignbit_b32
static __device__ __forceinline__ uint32_t funnel(uint32_t hi, uint32_t lo, int sh) {
    return (uint32_t)(((((uint64_t)hi) << 32) | (uint64_t)lo) >> sh);
}

// signed-byte dot4: HW v_dot4_i32_i8 when available (1 inst vs ~16)
static __device__ __forceinline__ int dot4(uint32_t a, uint32_t b, int c) {
#if __has_builtin(__builtin_amdgcn_sdot4)
    return __builtin_amdgcn_sdot4((int)a, (int)b, c, false);
#else
    int acc = c;
    #pragma unroll
    for (int i = 0; i < 4; ++i)
        acc += (int)(int8_t)(a >> (8*i)) * (int)(int8_t)(b >> (8*i));
    return acc;
#endif
}

// ---------------------------------------------------------------------------
// K0: quantize 1x1 weights into int8 matrix [128 co][128 k] in ws
//     k<64: w2q ; k>=64: wscq.  offs[co] = 128 * sum_k w2q[co][k]
//     (compensation for biased yq-128 B operand).  16-lane shuffle reduce.
// ---------------------------------------------------------------------------
__global__ void __launch_bounds__(256) wprep_kernel(
    const float* __restrict__ w2, const float* __restrict__ wsc,
    const float* __restrict__ sw2p, const float* __restrict__ swscp,
    int8_t* __restrict__ wbuf, int* __restrict__ offs)
{
    int t = blockIdx.x * 256 + threadIdx.x;   // 2048 threads, 4+4 weights each
    int f = t * 4;
    int co = f >> 6, k = f & 63;              // 16 consecutive threads per co
    float inv2 = 1.0f / sw2p[0];
    float invs = 1.0f / swscp[0];
    float4 a = *(const float4*)(w2 + f);
    float4 b = *(const float4*)(wsc + f);
    float av[4] = {a.x, a.y, a.z, a.w};
    float bv[4] = {b.x, b.y, b.z, b.w};
    uint32_t pa = 0, pb = 0;
    int partial = 0;
    #pragma unroll
    for (int j = 0; j < 4; ++j) {
        int qa = q8(av[j], inv2, -128.f, 127.f);
        int qb = q8(bv[j], invs, -128.f, 127.f);
        partial += qa;
        pa |= (uint32_t)(qa & 255) << (8*j);
        pb |= (uint32_t)(qb & 255) << (8*j);
    }
    *(uint32_t*)(wbuf + co*128 + k)      = pa;
    *(uint32_t*)(wbuf + co*128 + 64 + k) = pb;
    // reduce partial over the 16 threads sharing co (same wave)
    partial += __shfl_xor(partial, 1, 16);
    partial += __shfl_xor(partial, 2, 16);
    partial += __shfl_xor(partial, 4, 16);
    partial += __shfl_xor(partial, 8, 16);
    if ((t & 15) == 0) offs[co] = partial << 7;
}

// ---------------------------------------------------------------------------
// K1 (fused, 1 row/block, 896 blocks):
//   XCD swizzle: n = bid&7, h = bid>>3 — each image (x slice 3.2MB < 4MB L2)
//   stays on one XCD with all 112 row-blocks co-resident. Output stores are
//   NON-TEMPORAL (nt) so the 6.4MB/image write stream does not evict the
//   3.2MB x slice from the 4MB XCD L2 -> halo rows (each x row read by 3
//   blocks) stay L2-hits -> x HBM-fetched ~1x.
//   ph0: hoisted loads — w1 taps, int8 weight fragments, offs
//   ph1: x loads in 3 batches of 7 float4 -> quant -> tile
//   ph2: depthwise 3x3 (sdot4) + relu-quant -> Bl int8 [112 px][144]
//        (k 0..63 = yq-128 biased, 64..127 = xq)
//   ph3: mfma_i32_16x16x64_i8 with A=activations, B=weights (operand swap):
//        D regs/lane = 4 consecutive px of one co row -> v4f nt stores.
//        offs folded into MFMA C operand (integer accumulate is exact);
//        1/sadd folded into the two scale factors.
// LDS = 22272 + 16128 = 38400 B -> 4 blocks/CU; launch_bounds(256,4).
// ---------------------------------------------------------------------------
__global__ void __launch_bounds__(256, 4) fused_kernel(
    const float* __restrict__ x, const float* __restrict__ w1,
    const int8_t* __restrict__ wbuf, const int* __restrict__ offs,
    const float* __restrict__ sinp, const float* __restrict__ srelup,
    const float* __restrict__ saddp, const float* __restrict__ sw1p,
    const float* __restrict__ sw2p, const float* __restrict__ swscp,
    float* __restrict__ out)
{
    __shared__ int8_t tile[64 * 348];   // c-stride 348 B (87 dwords, odd)
    __shared__ int8_t Bl[112 * 144];    // px-stride 144 B (16B-aligned for b128)

    int bid = blockIdx.x;
    int n = bid & 7, h = bid >> 3;      // XCD-pinned image, sequential rows
    int tid = threadIdx.x;
    int wave = tid >> 6, lane = tid & 63;
    int lr = lane >> 4, ln = lane & 15;
    float sin_f = sinp[0];
    float inv_sin = 1.0f / sin_f;

    // ---- phase 0a: depthwise taps for this thread's channel ----
    int c = lane;
    float isw1 = 1.0f / sw1p[0];
    uint32_t wp[3];
    #pragma unroll
    for (int ky = 0; ky < 3; ++ky) {
        uint32_t pk = 0;
        #pragma unroll
        for (int kx = 0; kx < 3; ++kx) {
            int q = q8(w1[c*9 + ky*3 + kx], isw1, -128.0f, 127.0f);
            pk |= (uint32_t)(q & 255) << (8*kx);
        }
        wp[ky] = pk;
    }

    // ---- phase 0b: int8 weight fragments + per-co offsets (L2-resident) ----
    // a[mi][half]: co = (wave*2+mi)*16 + ln, k-bytes = half*64 + lr*16 .. +15
    v4i a[2][2];
    int ofsv[2];
    #pragma unroll
    for (int mi = 0; mi < 2; ++mi) {
        int mt = wave*2 + mi;
        int m = mt*16 + ln;
        a[mi][0] = *(const v4i*)(wbuf + (size_t)m*128 + lr*16);
        a[mi][1] = *(const v4i*)(wbuf + (size_t)m*128 + 64 + lr*16);
        ofsv[mi] = offs[m];
    }

    // ---- phase 1: 3 batches of 7 float4 (28 VGPRs in flight) ----
    #pragma unroll
    for (int b = 0; b < 3; ++b) {
        float4 vals[7];
        #pragma unroll
        for (int i = 0; i < 7; ++i) {
            int id = tid + (b*7 + i)*256;
            int cc = id / 84; int rem = id - cc*84;
            int r = rem / 28; int seg = rem - r*28;
            int grow = h + r - 1;
            vals[i] = make_float4(0.f, 0.f, 0.f, 0.f);
            if ((unsigned)grow < 112u)
                vals[i] = *(const float4*)(x + ((size_t)(n*64 + cc) * HWI + grow*112 + seg*4));
        }
        #pragma unroll
        for (int i = 0; i < 7; ++i) {
            int id = tid + (b*7 + i)*256;
            int cc = id / 84; int rem = id - cc*84;
            int r = rem / 28; int seg = rem - r*28;
            float vv[4] = {vals[i].x, vals[i].y, vals[i].z, vals[i].w};
            uint32_t pk = 0;
            #pragma unroll
            for (int e = 0; e < 4; ++e) {
                int q = q8(vv[e], inv_sin, -128.0f, 127.0f);
                pk |= (uint32_t)(q & 255) << (8*e);
            }
            *(uint32_t*)&tile[cc*348 + r*116 + seg*4] = pk;
        }
    }
    if (tid < 192) {  // zero pad cols 112..115 of each (c, r)
        int cc = tid / 3, r = tid - cc*3;
        *(uint32_t*)&tile[cc*348 + r*116 + 112] = 0;
    }
    __syncthreads();

    // ---- phase 2: depthwise 3x3 + relu-quant; int8 yq-128 / xq into Bl ----
    {
        int w0b = wave * 28;              // 28-px quarter of the row
        float r1 = (sin_f * sw1p[0]) / srelup[0];

        int base[3];
        #pragma unroll
        for (int r2 = 0; r2 < 3; ++r2) base[r2] = c*348 + r2*116;

        uint32_t Ar[3], Br[3], Cr[3];
        #pragma unroll
        for (int r2 = 0; r2 < 3; ++r2) {
            Ar[r2] = wave ? *(uint32_t*)&tile[base[r2] + w0b - 4] : 0u;
            Br[r2] = *(uint32_t*)&tile[base[r2] + w0b];
            Cr[r2] = *(uint32_t*)&tile[base[r2] + w0b + 4];
        }

        #pragma unroll
        for (int q = 0; q < 7; ++q) {
            int acc0 = 0, acc1 = 0, acc2 = 0, acc3 = 0;
            #pragma unroll
            for (int r2 = 0; r2 < 3; ++r2) {
                uint32_t d0 = funnel(Br[r2], Ar[r2], 24);
                uint32_t d1 = Br[r2];
                uint32_t d2 = funnel(Cr[r2], Br[r2], 8);
                uint32_t d3 = funnel(Cr[r2], Br[r2], 16);
                acc0 = dot4(d0, wp[r2], acc0);
                acc1 = dot4(d1, wp[r2], acc1);
                acc2 = dot4(d2, wp[r2], acc2);
                acc3 = dot4(d3, wp[r2], acc3);
            }
            int accs[4] = {acc0, acc1, acc2, acc3};
            uint32_t xdw = Br[1];
            int pxb = w0b + q*4;
            #pragma unroll
            for (int j = 0; j < 4; ++j) {
                float t = rintf((float)accs[j] * r1);
                t = fminf(fmaxf(t, 0.0f), 255.0f);
                Bl[(pxb + j)*144 + c]      = (int8_t)((int)t - 128);         // yq-128
                Bl[(pxb + j)*144 + 64 + c] = (int8_t)((xdw >> (8*j)) & 255); // xq
            }
            #pragma unroll
            for (int r2 = 0; r2 < 3; ++r2) { Ar[r2] = Br[r2]; Br[r2] = Cr[r2]; }
            if (q < 6) {
                #pragma unroll
                for (int r2 = 0; r2 < 3; ++r2)
                    Cr[r2] = *(uint32_t*)&tile[base[r2] + w0b + q*4 + 8];
            }
        }
    }
    __syncthreads();

    // ---- phase 3: GEMM (mfma, A=act B=weight) + requant, nt v4f stores ----
    {
        float sadd = saddp[0];
        float inv_sadd = 1.0f / sadd;
        float S2i  = (sw2p[0] * srelup[0]) * inv_sadd;
        float Ssci = (swscp[0] * sin_f)    * inv_sadd;

        size_t orow = (size_t)n*COUT*HWI + (size_t)h*112;

        for (int nt = 0; nt < 7; ++nt) {
            int px = nt*16 + ln;                     // A-fragment row index
            const int8_t* bp = &Bl[px*144 + lr*16];
            v4i b0 = *(const v4i*)bp;          // yq-128 bytes (k<64)
            v4i b1 = *(const v4i*)(bp + 64);   // xq bytes   (k>=64)
            int pxb = nt*16 + lr*4;                  // D rows: 4 consecutive px
            #pragma unroll
            for (int mi = 0; mi < 2; ++mi) {
                v4i z = {0, 0, 0, 0};
                v4i cini = {ofsv[mi], ofsv[mi], ofsv[mi], ofsv[mi]};
                // operand swap: A = activations, B = weights; offs in C operand
                v4i c2 = __builtin_amdgcn_mfma_i32_16x16x64_i8(b0, a[mi][0], cini, 0, 0, 0);
                v4i cs = __builtin_amdgcn_mfma_i32_16x16x64_i8(b1, a[mi][1], z, 0, 0, 0);
                int co = (wave*2 + mi)*16 + ln;
                v4f vr;
                #pragma unroll
                for (int r = 0; r < 4; ++r) {
                    float t = rintf(S2i * (float)c2[r] + Ssci * (float)cs[r]);
                    t = fminf(fmaxf(t, -128.0f), 127.0f);
                    vr[r] = t * sadd;
                }
                // non-temporal: don't let the output stream evict x from L2
                __builtin_nontemporal_store(vr,
                    (v4f*)(out + orow + (size_t)co*HWI + pxb));
            }
        }
    }
}

// ---------------------------------------------------------------------------
extern "C" void kernel_launch(void* const* d_in, const int* in_sizes, int n_in,
                              void* d_out, int out_size, void* d_ws, size_t ws_size,
                              hipStream_t stream) {
    const float* x     = (const float*)d_in[0];
    const float* w1    = (const float*)d_in[1];
    const float* w2    = (const float*)d_in[2];
    const float* wsc   = (const float*)d_in[3];
    const float* sin   = (const float*)d_in[4];
    const float* srelu = (const float*)d_in[5];
    const float* sadd  = (const float*)d_in[6];
    const float* sw1   = (const float*)d_in[7];
    const float* sw2   = (const float*)d_in[8];
    const float* swsc  = (const float*)d_in[9];

    int8_t* wbuf = (int8_t*)d_ws;                      // 16 KB int8 weights
    int*    offs = (int*)(wbuf + (size_t)COUT * 128);  // 512 B

    wprep_kernel<<<8, 256, 0, stream>>>(w2, wsc, sw2, swsc, wbuf, offs);
    fused_kernel<<<NIMG * 112, 256, 0, stream>>>(x, w1, wbuf, offs,
                                                 sin, srelu, sadd, sw1, sw2, swsc,
                                                 (float*)d_out);
}